// Round 3
// baseline (1410.578 us; speedup 1.0000x reference)
//
#include <hip/hip_runtime.h>

// EncoderGRUODE: B=256, T=512, D_IN=64, H=128
// One 512-thread workgroup per sample, persistent over all 512 steps.
// R3: q=16 k-split (group = 16 lanes owns 4 rows). Thread reads 8 h-floats
// (2 ds_read_b128) per matvec, reused over 4 rows -> LDS reads 45->13/step.
// Reductions: DPP row_shr prefix scans (no swizzle/LDS), then quad_perm(3333)
// bcast + cndmask regroup: lanes 12..15 of each group hold rows 4g+0..3.
// Elementwise/transcendental work runs once per thread (on lanes 12..15).
// amdgpu_waves_per_eu(2,2): cap occupancy at 2 waves/EU so the allocator has
// no incentive to stay under 256 VGPRs -> 192-reg weight set stays resident
// (R1/R2 failure mode: heuristic chose 128 VGPRs and spilled/reloaded the
// weights each step = L2-BW-bound at ~1.2-1.5 ms).

#define NB    256
#define TB    512
#define TSTEP 512
#define DIN   64
#define HD    128

typedef float v2f __attribute__((ext_vector_type(2)));

__device__ __forceinline__ float fast_tanh(float v) {
    float e = __expf(2.0f * v);
    return 1.0f - 2.0f / (e + 1.0f);
}
__device__ __forceinline__ float fast_sigmoid(float v) {
    return 1.0f / (1.0f + __expf(-v));
}

template<int CTRL>
__device__ __forceinline__ float dpp_add(float v) {
    return v + __int_as_float(__builtin_amdgcn_update_dpp(
        0, __float_as_int(v), CTRL, 0xF, 0xF, true));
}
// prefix-sum over the 16-lane DPP row; lane 15 (of each row) = total
__device__ __forceinline__ float scan16(float v) {
    v = dpp_add<0x111>(v);  // row_shr:1
    v = dpp_add<0x112>(v);  // row_shr:2
    v = dpp_add<0x114>(v);  // row_shr:4
    v = dpp_add<0x118>(v);  // row_shr:8
    return v;
}
// quad_perm [3,3,3,3]: every lane gets its quad's lane-3 value.
// For lanes 12..15 that is lane 15 = the scan16 total.
__device__ __forceinline__ float qp3333(float v) {
    return __int_as_float(__builtin_amdgcn_update_dpp(
        0, __float_as_int(v), 0xFF, 0xF, 0xF, true));
}

__global__ __launch_bounds__(TB) __attribute__((amdgpu_waves_per_eu(2, 2)))
void gruode_kernel(
    const float* __restrict__ x,         // [B, T, DIN]
    const float* __restrict__ tp,        // [B, T] (row 0 used)
    const int*   __restrict__ samp_mask, // [T]
    const float* __restrict__ W_ih,      // [3H, DIN]
    const float* __restrict__ W_hh,      // [3H, H]
    const float* __restrict__ b_ih,      // [3H]
    const float* __restrict__ b_hh,      // [3H]
    const float* __restrict__ W_node,    // [H, H]
    const float* __restrict__ b_node,    // [H]
    const float* __restrict__ W_out,     // [DIN, H]
    const float* __restrict__ b_out,     // [DIN]
    float*       __restrict__ out)       // [B*T, DIN]
{
    const int t    = threadIdx.x;
    const int b    = blockIdx.x;
    const int g    = t >> 4;       // group 0..31  (owns rows 4g..4g+3; out rows 2g..2g+1)
    const int kk   = t & 15;       // k-lane: h-slice floats kk*8..+7, in-slice kk*4..+3
    const int rsel = kk & 3;       // after regroup, lanes 12..15 hold row 4g+rsel

    __shared__ __align__(16) float sh_h [HD];
    __shared__ __align__(16) float sh_t0[HD];
    __shared__ __align__(16) float sh_t1[HD];
    __shared__ __align__(16) float sh_po[DIN];

    const float4* Wn4  = (const float4*)W_node;  // [128][32 f4]
    const float4* Whh4 = (const float4*)W_hh;    // [384][32 f4]
    const float4* Wih4 = (const float4*)W_ih;    // [384][16 f4]
    const float4* Wo4  = (const float4*)W_out;   // [64][32 f4]

    // ---- weights -> registers: 4 rows x 8 floats (v2f[4][4]) per 128-dim mat,
    //      4 rows x 4 floats (v2f[4][2]) per 64-dim mat, 2 rows x 8 for W_out.
    v2f Wn[4][4], Whr[4][4], Whz[4][4], Whn[4][4];
    v2f Wir[4][2], Wiz[4][2], Win[4][2];
    v2f Wo[2][4];
    #pragma unroll
    for (int r = 0; r < 4; ++r) {
        const int row = 4*g + r;
        float4 a, c;
        a = Wn4[row*32 + 2*kk];  c = Wn4[row*32 + 2*kk + 1];
        Wn[r][0]=(v2f){a.x,a.y}; Wn[r][1]=(v2f){a.z,a.w}; Wn[r][2]=(v2f){c.x,c.y}; Wn[r][3]=(v2f){c.z,c.w};
        a = Whh4[(0*HD+row)*32 + 2*kk];  c = Whh4[(0*HD+row)*32 + 2*kk + 1];
        Whr[r][0]=(v2f){a.x,a.y}; Whr[r][1]=(v2f){a.z,a.w}; Whr[r][2]=(v2f){c.x,c.y}; Whr[r][3]=(v2f){c.z,c.w};
        a = Whh4[(1*HD+row)*32 + 2*kk];  c = Whh4[(1*HD+row)*32 + 2*kk + 1];
        Whz[r][0]=(v2f){a.x,a.y}; Whz[r][1]=(v2f){a.z,a.w}; Whz[r][2]=(v2f){c.x,c.y}; Whz[r][3]=(v2f){c.z,c.w};
        a = Whh4[(2*HD+row)*32 + 2*kk];  c = Whh4[(2*HD+row)*32 + 2*kk + 1];
        Whn[r][0]=(v2f){a.x,a.y}; Whn[r][1]=(v2f){a.z,a.w}; Whn[r][2]=(v2f){c.x,c.y}; Whn[r][3]=(v2f){c.z,c.w};
        a = Wih4[(0*HD+row)*16 + kk];
        Wir[r][0]=(v2f){a.x,a.y}; Wir[r][1]=(v2f){a.z,a.w};
        a = Wih4[(1*HD+row)*16 + kk];
        Wiz[r][0]=(v2f){a.x,a.y}; Wiz[r][1]=(v2f){a.z,a.w};
        a = Wih4[(2*HD+row)*16 + kk];
        Win[r][0]=(v2f){a.x,a.y}; Win[r][1]=(v2f){a.z,a.w};
    }
    #pragma unroll
    for (int r = 0; r < 2; ++r) {
        const int row = 2*g + r;
        float4 a = Wo4[row*32 + 2*kk], c = Wo4[row*32 + 2*kk + 1];
        Wo[r][0]=(v2f){a.x,a.y}; Wo[r][1]=(v2f){a.z,a.w}; Wo[r][2]=(v2f){c.x,c.y}; Wo[r][3]=(v2f){c.z,c.w};
    }
    // pin against remat/sinking
    #pragma unroll
    for (int r = 0; r < 4; ++r) {
        #pragma unroll
        for (int i = 0; i < 4; ++i) {
            asm volatile("" : "+v"(Wn[r][i]));  asm volatile("" : "+v"(Whr[r][i]));
            asm volatile("" : "+v"(Whz[r][i])); asm volatile("" : "+v"(Whn[r][i]));
        }
        asm volatile("" : "+v"(Wir[r][0])); asm volatile("" : "+v"(Wir[r][1]));
        asm volatile("" : "+v"(Wiz[r][0])); asm volatile("" : "+v"(Wiz[r][1]));
        asm volatile("" : "+v"(Win[r][0])); asm volatile("" : "+v"(Win[r][1]));
    }
    #pragma unroll
    for (int i = 0; i < 4; ++i) {
        asm volatile("" : "+v"(Wo[0][i])); asm volatile("" : "+v"(Wo[1][i]));
    }

    // per-lane biases for the row this lane will own after regroup
    const int rl  = 4*g + rsel;
    const float bn   = b_node[rl];
    const float br   = b_ih[0*HD + rl] + b_hh[0*HD + rl];
    const float bz   = b_ih[1*HD + rl] + b_hh[1*HD + rl];
    const float bin  = b_ih[2*HD + rl];
    const float bhn  = b_hh[2*HD + rl];
    const float bo   = b_out[2*g + (rsel & 1)];

    if (t < HD)  sh_h[t]  = 0.0f;     // h0 = 0
    if (t < DIN) sh_po[t] = b_out[t]; // prev_out(h0) = b_out

    // uniform stream state (SGPR) + per-lane x prefetch
    float tp_cur  = tp[0];
    float tp_prev = tp_cur - 0.01f;   // dts[0] = 0.01
    int   m_cur   = samp_mask[0];
    const float4* x4 = (const float4*)x;
    float4 xr = x4[(size_t)b * TSTEP * 16 + kk];   // x[b][0][kk*4..+3]

    __syncthreads();

    const float4* h4  = (const float4*)sh_h;
    const float4* t04 = (const float4*)sh_t0;
    const float4* t14 = (const float4*)sh_t1;
    const float4* po4 = (const float4*)sh_po;

    // 4-row k-sliced partial dot over a 128-float LDS vector
    auto dot128 = [&](const v2f (&w)[4][4], const float4* buf, float (&acc)[4]) {
        float4 a = buf[2*kk], c = buf[2*kk + 1];
        v2f x0 = {a.x, a.y}, x1 = {a.z, a.w}, x2 = {c.x, c.y}, x3 = {c.z, c.w};
        #pragma unroll
        for (int r = 0; r < 4; ++r) {
            v2f s = w[r][0] * x0;
            s = w[r][1] * x1 + s;
            s = w[r][2] * x2 + s;
            s = w[r][3] * x3 + s;
            acc[r] = s.x + s.y;
        }
    };
    // reduce 4 partials over 16 lanes; lanes 12..15 return row 4g+(kk&3)'s sum
    auto reduce4 = [&](const float (&acc)[4]) -> float {
        float s0 = qp3333(scan16(acc[0]));
        float s1 = qp3333(scan16(acc[1]));
        float s2 = qp3333(scan16(acc[2]));
        float s3 = qp3333(scan16(acc[3]));
        return rsel == 0 ? s0 : rsel == 1 ? s1 : rsel == 2 ? s2 : s3;
    };

    float hj = 0.0f;   // lanes 12..15: h[4g+rsel], carried across steps

    #pragma unroll 1
    for (int s = 0; s < TSTEP; ++s) {
        const float dt = tp_cur - tp_prev;
        float acc[4], p, k1, k2, k3, k4;

        // ---- RK4 on dh/dt = tanh(Wn h + bn) ----
        dot128(Wn, h4, acc);
        p  = reduce4(acc);
        k1 = fast_tanh(p + bn);
        if (kk >= 12) sh_t0[4*g + rsel] = fmaf(0.5f * dt, k1, hj);
        __syncthreads();                                   // B1

        dot128(Wn, t04, acc);
        p  = reduce4(acc);
        k2 = fast_tanh(p + bn);
        if (kk >= 12) sh_t1[4*g + rsel] = fmaf(0.5f * dt, k2, hj);
        __syncthreads();                                   // B2

        dot128(Wn, t14, acc);
        p  = reduce4(acc);
        k3 = fast_tanh(p + bn);
        if (kk >= 12) sh_t0[4*g + rsel] = fmaf(dt, k3, hj);
        __syncthreads();                                   // B3

        dot128(Wn, t04, acc);
        p  = reduce4(acc);
        k4 = fast_tanh(p + bn);
        const float hode = fmaf(dt * (1.0f / 6.0f),
                                (k1 + 2.0f * k2) + (2.0f * k3 + k4), hj);
        if (kk >= 12) sh_t1[4*g + rsel] = hode;            // t1 = h_ode vector
        __syncthreads();                                   // B4

        // ---- GRU cell: hidden from t1 (h_ode), input from x or prev_out ----
        {
            float4 a = t14[2*kk], c = t14[2*kk + 1];
            v2f h0 = {a.x, a.y}, h1 = {a.z, a.w}, h2 = {c.x, c.y}, h3 = {c.z, c.w};
            float4 vi;
            if (m_cur) vi = xr; else vi = po4[kk];
            v2f i0 = {vi.x, vi.y}, i1 = {vi.z, vi.w};

            float aR[4], aZ[4], aNh[4], aNi[4];
            #pragma unroll
            for (int r = 0; r < 4; ++r) {
                v2f sR = Whr[r][0]*h0; sR = Whr[r][1]*h1 + sR;
                sR = Whr[r][2]*h2 + sR; sR = Whr[r][3]*h3 + sR;
                sR = Wir[r][0]*i0 + sR; sR = Wir[r][1]*i1 + sR;
                aR[r] = sR.x + sR.y;
                v2f sZ = Whz[r][0]*h0; sZ = Whz[r][1]*h1 + sZ;
                sZ = Whz[r][2]*h2 + sZ; sZ = Whz[r][3]*h3 + sZ;
                sZ = Wiz[r][0]*i0 + sZ; sZ = Wiz[r][1]*i1 + sZ;
                aZ[r] = sZ.x + sZ.y;
                v2f sH = Whn[r][0]*h0; sH = Whn[r][1]*h1 + sH;
                sH = Whn[r][2]*h2 + sH; sH = Whn[r][3]*h3 + sH;
                aNh[r] = sH.x + sH.y;
                v2f sI = Win[r][0]*i0; sI = Win[r][1]*i1 + sI;
                aNi[r] = sI.x + sI.y;
            }
            float R  = reduce4(aR);
            float Z  = reduce4(aZ);
            float Nh = reduce4(aNh);
            float Ni = reduce4(aNi);

            float rr = fast_sigmoid(R + br);
            float zz = fast_sigmoid(Z + bz);
            float nn = fast_tanh(fmaf(rr, Nh + bhn, Ni + bin));
            float hnew = fmaf(zz, hode - nn, nn);          // (1-z)n + z*h_ode
            hj = hnew;
            if (kk >= 12) sh_h[4*g + rsel] = hnew;
        }

        // prefetch next step's stream data (covered by B5..next B4 slack)
        {
            const int sn = (s + 1 < TSTEP) ? s + 1 : s;
            tp_prev = tp_cur;
            tp_cur  = tp[sn];
            m_cur   = samp_mask[sn];
            xr = x4[((size_t)b * TSTEP + sn) * 16 + kk];
        }
        __syncthreads();                                   // B5

        // ---- out_t = h_new @ W_out^T + b_out (also next step's prev_out) ---
        {
            float4 a = h4[2*kk], c = h4[2*kk + 1];
            v2f x0 = {a.x, a.y}, x1 = {a.z, a.w}, x2 = {c.x, c.y}, x3 = {c.z, c.w};
            float o01[2];
            #pragma unroll
            for (int r = 0; r < 2; ++r) {
                v2f s2_ = Wo[r][0]*x0; s2_ = Wo[r][1]*x1 + s2_;
                s2_ = Wo[r][2]*x2 + s2_; s2_ = Wo[r][3]*x3 + s2_;
                o01[r] = s2_.x + s2_.y;
            }
            float so0 = qp3333(scan16(o01[0]));
            float so1 = qp3333(scan16(o01[1]));
            float o = ((rsel & 1) ? so1 : so0) + bo;
            if (kk == 12 || kk == 13) {                    // rows 2g+0, 2g+1
                const int col = 2*g + rsel;
                sh_po[col] = o;
                out[((size_t)b * TSTEP + s) * DIN + col] = o;
            }
        }
        // no barrier here: sh_po/sh_h next read only after B4/B1 of step s+1
    }
}

extern "C" void kernel_launch(void* const* d_in, const int* in_sizes, int n_in,
                              void* d_out, int out_size, void* d_ws, size_t ws_size,
                              hipStream_t stream) {
    (void)in_sizes; (void)n_in; (void)d_ws; (void)ws_size; (void)out_size;
    const float* x      = (const float*)d_in[0];
    const float* tp     = (const float*)d_in[1];
    const int*   mask   = (const int*)  d_in[2];
    const float* W_ih   = (const float*)d_in[3];
    const float* W_hh   = (const float*)d_in[4];
    const float* b_ih   = (const float*)d_in[5];
    const float* b_hh   = (const float*)d_in[6];
    const float* W_node = (const float*)d_in[7];
    const float* b_node = (const float*)d_in[8];
    const float* W_out  = (const float*)d_in[9];
    const float* b_out  = (const float*)d_in[10];
    float* outp = (float*)d_out;

    gruode_kernel<<<NB, TB, 0, stream>>>(x, tp, mask, W_ih, W_hh, b_ih, b_hh,
                                         W_node, b_node, W_out, b_out, outp);
}